// Round 11
// baseline (274.551 us; speedup 1.0000x reference)
//
#include <hip/hip_runtime.h>

// F0 via autocorrelation argmax — round 11: multi-frame waves, no spill.
//   SR=16000, HOP=256, FRAME_LEN=512, pad=256, T=163840, B=64, n_frames=641
//   lags p in [32,256). Normalization is a positive per-frame scalar ->
//   argmax of RAW autocorrelation equals reference argmax.
//
// GEMM cast (validated r8/r9, absmax 0.0): y = frame zero-extended,
//   A[m,k]=y[k-16m], B[k,n]=y[k+32+n] => D[m,n]=AC[32+16m+n]
//   16 mfma_f32_16x16x32_f16 (K=512), two parity LDS copies for B-align,
//   2 independent accumulator chains for ILP.
//
// Round-10 lesson (counters): __launch_bounds__(256,8) -> VGPR=32 ->
// tier-2/3 register tiles spilled (WRITE_SIZE 2.5MB->174MB, dur 82->188us).
// NEVER bound below the fat path's ~110 VGPR: use (256,4).
// Round-9 lesson: one-frame waves live ~2.5us; average concurrency ~5
// waves/CU -> latency never hidden. Fix: each wave processes 8 CONSECUTIVE
// frames (75% sample overlap, L2-hot) in a loop; grid 41024/32 = 1282.
//
// Tiers: accept iff top2 gap > 2*E1, E1 = 2^-10*Q + 0.05 (f16 products,
// Cauchy-Schwarz; fp32 accum slack). Tier-2 fp32 register tile (r7-proven):
// gap > 0.0625. Tier-3 fp64 register tile: exact argmax (np-exact r1-r10).

#define SR_F 16000.0f
#define HOP 256
#define FRAME_LEN 512
#define PAD 256
#define T_LEN 163840
#define N_FRAMES 641
#define MIN_PERIOD 32
#define N_LAGS 224
#define WPB 4            // waves per block
#define FPW 8            // frames per wave
#define GAP_B32 0.0625f

typedef _Float16 half8 __attribute__((ext_vector_type(8)));
typedef float floatx4 __attribute__((ext_vector_type(4)));

__device__ __forceinline__ int swz(int q) { return q ^ ((q >> 3) & 7); }

__device__ __forceinline__ unsigned int pkh(float a, float b) {
    unsigned short ha = __builtin_bit_cast(unsigned short, (_Float16)a);
    unsigned short hb = __builtin_bit_cast(unsigned short, (_Float16)b);
    return (unsigned int)ha | ((unsigned int)hb << 16);
}

__global__ __launch_bounds__(256, 4) void f0_kernel(const float* __restrict__ wav,
                                                    float* __restrict__ out) {
    // per-wave slice: ye(400 dwords) + yo(400 dwords) = 3200 B
    __shared__ unsigned int yw[WPB][800];

    const int tid  = threadIdx.x;
    const int wv   = tid >> 6;
    const int lane = tid & 63;
    unsigned int* ye = yw[wv];
    unsigned int* yo = ye + 400;

    const int qd = lane >> 4;       // quad
    const int nn = lane & 15;       // A-row m / B-col n
    const int par = nn & 1;
    const unsigned int* ybh = par ? yo : ye;
    const int wA0 = 120 + 4*qd - 8*nn;
    const int wB0 = 136 + 4*qd + ((nn - par) >> 1);
    const int seg = lane & 15;
    const bool s0 = (seg & 1), s1 = (seg & 2), s2 = (seg & 4), s3 = (seg & 8);

    const int bf0 = (blockIdx.x * WPB + wv) * FPW;   // 1282*4*8 == 41024

    for (int it = 0; it < FPW; ++it) {
        const int bf = bf0 + it;
        const int b  = bf / N_FRAMES;
        const int f  = bf - b * N_FRAMES;
        const float* __restrict__ x = wav + (size_t)b * T_LEN;
        const int base = f * HOP - PAD;
        const bool fast = (f != 0 && f != N_FRAMES - 1);

        // ---- stage frame (f16 hi, two parity copies) ----
        float4 c1, c2;
        if (fast) {
            const float4* g4 = (const float4*)(x + base);
            c1 = g4[lane];
            c2 = g4[lane + 64];
        }
        // zero margins: dwords [0,120) and [375,400) of both copies
        ye[lane] = 0u; yo[lane] = 0u;
        if (lane < 56) { ye[64 + lane] = 0u; yo[64 + lane] = 0u; }
        if (lane < 25) { ye[375 + lane] = 0u; yo[375 + lane] = 0u; }

        float qen = 0.0f;
        if (fast) {
            qen = c1.x*c1.x + c1.y*c1.y + c1.z*c1.z + c1.w*c1.w
                + c2.x*c2.x + c2.y*c2.y + c2.z*c2.z + c2.w*c2.w;
            unsigned int u10 = pkh(c1.x, c1.y), u11 = pkh(c1.z, c1.w);
            unsigned int u20 = pkh(c2.x, c2.y), u21 = pkh(c2.z, c2.w);
            ye[120 + 2*lane] = u10;  ye[121 + 2*lane] = u11;
            ye[248 + 2*lane] = u20;  ye[249 + 2*lane] = u21;
            unsigned int a  = __shfl(u10, (lane + 1) & 63);
            unsigned int bb = __shfl(u20, (lane + 1) & 63);
            unsigned int n1 = (lane == 63) ? bb : a;
            unsigned int n2 = (lane == 63) ? 0u : bb;
            yo[120 + 2*lane] = (u10 >> 16) | (u11 << 16);
            yo[121 + 2*lane] = (u11 >> 16) | (n1 << 16);
            yo[248 + 2*lane] = (u20 >> 16) | (u21 << 16);
            yo[249 + 2*lane] = (u21 >> 16) | (n2 << 16);
            if (lane == 0) yo[119] = u10 << 16;   // {Y[-1]=0, Y[0]}
        } else {
            for (int t = lane; t < FRAME_LEN; t += 64) {
                int idx = base + t;
                if (idx < 0) idx = -idx;
                if (idx >= T_LEN) idx = 2 * (T_LEN - 1) - idx;
                float v = x[idx];
                qen = __builtin_fmaf(v, v, qen);
                unsigned short h = __builtin_bit_cast(unsigned short, (_Float16)v);
                ((unsigned short*)ye)[240 + t] = h;
                ((unsigned short*)yo)[239 + t] = h;
            }
        }
        __threadfence_block();

        #pragma unroll
        for (int m = 1; m < 64; m <<= 1) qen += __shfl_xor(qen, m);

        // ---------------- tier-1: 16 MFMA (2 chains) ----------------
        floatx4 acc0 = {0.f, 0.f, 0.f, 0.f};
        floatx4 acc1 = {0.f, 0.f, 0.f, 0.f};
        #pragma unroll
        for (int c = 0; c < 16; c += 2) {
            uint4 au0 = *(const uint4*)(ye + (wA0 + 16*c));
            const unsigned int* pb0 = ybh + (wB0 + 16*c);
            uint4 bu0; bu0.x=pb0[0]; bu0.y=pb0[1]; bu0.z=pb0[2]; bu0.w=pb0[3];
            uint4 au1 = *(const uint4*)(ye + (wA0 + 16*(c+1)));
            const unsigned int* pb1 = ybh + (wB0 + 16*(c+1));
            uint4 bu1; bu1.x=pb1[0]; bu1.y=pb1[1]; bu1.z=pb1[2]; bu1.w=pb1[3];
            acc0 = __builtin_amdgcn_mfma_f32_16x16x32_f16(
                __builtin_bit_cast(half8, au0), __builtin_bit_cast(half8, bu0),
                acc0, 0, 0, 0);
            acc1 = __builtin_amdgcn_mfma_f32_16x16x32_f16(
                __builtin_bit_cast(half8, au1), __builtin_bit_cast(half8, bu1),
                acc1, 0, 0, 0);
        }
        floatx4 acc = acc0 + acc1;

        // ---- top-2 (per-lane over 4 regs, then 64-lane butterfly) ----
        float v1 = acc[0];
        int   i1 = 64*qd + nn;
        float v2 = -__builtin_inff();
        #pragma unroll
        for (int r = 1; r < 4; ++r) {
            float cv = (4*qd + r < 14) ? acc[r] : -__builtin_inff();
            bool take = (cv > v1);
            float lose = take ? v1 : cv;
            if (take) { v1 = cv; i1 = 64*qd + 16*r + nn; }
            v2 = fmaxf(v2, lose);
        }
        #pragma unroll
        for (int m = 1; m < 64; m <<= 1) {
            float ov1 = __shfl_xor(v1, m);
            float ov2 = __shfl_xor(v2, m);
            int   oi1 = __shfl_xor(i1, m);
            bool take = (ov1 > v1) || (ov1 == v1 && oi1 < i1);
            float lose = take ? v1 : ov1;
            if (take) { v1 = ov1; i1 = oi1; }
            v2 = fmaxf(fmaxf(v2, ov2), lose);
        }

        const float E1 = 9.765625e-4f * qen + 0.05f;
        if (v1 - v2 > 2.0f * E1) {
            if (lane == 0) {
                float period = (float)(i1 + MIN_PERIOD);
                float f0 = SR_F / (period + 1e-8f);
                out[bf] = fminf(fmaxf(f0, 50.0f), 500.0f);
            }
            continue;
        }

        // ======== tier-2: fp32 register tile (r7-proven), ~10% ========
        float* sw = (float*)ye;
        if (fast) {
            const float4* g4 = (const float4*)(x + base);   // L2-hot reload
            ((float4*)sw)[swz(lane)]      = g4[lane];
            ((float4*)sw)[swz(lane + 64)] = g4[lane + 64];
            if (lane < 16) ((float4*)sw)[swz(lane + 128)] = make_float4(0.f,0.f,0.f,0.f);
        } else {
            for (int t = lane; t < FRAME_LEN; t += 64) {
                int idx = base + t;
                if (idx < 0) idx = -idx;
                if (idx >= T_LEN) idx = 2 * (T_LEN - 1) - idx;
                sw[(swz(t >> 2) << 2) | (t & 3)] = x[idx];
            }
            int t = FRAME_LEN + lane;
            sw[(swz(t >> 2) << 2) | (t & 3)] = 0.0f;
        }
        __threadfence_block();

        const float4* s4 = (const float4*)sw;
        float tot[4];
        #pragma unroll
        for (int r = 0; r < 4; ++r) {
            const int g  = (r << 2) + qd;
            const int p0 = MIN_PERIOD + (g << 4);
            float acc2[16];
            #pragma unroll
            for (int j = 0; j < 16; ++j) acc2[j] = 0.0f;
            if (g < 14) {
                const int n16 = (FRAME_LEN - p0 + 15) >> 4;
                #pragma unroll
                for (int k = 0; k < 2; ++k) {
                    const int ch = seg + (k << 4);
                    if (ch < n16) {
                        const int t  = ch << 4;
                        const int qa = t >> 2;
                        const int qw = (t + p0) >> 2;
                        float a[16], w[32];
                        #pragma unroll
                        for (int u = 0; u < 4; ++u) {
                            float4 v = s4[swz(qa + u)];
                            a[4*u+0]=v.x; a[4*u+1]=v.y; a[4*u+2]=v.z; a[4*u+3]=v.w;
                        }
                        #pragma unroll
                        for (int u = 0; u < 8; ++u) {
                            float4 v = s4[swz(qw + u)];
                            w[4*u+0]=v.x; w[4*u+1]=v.y; w[4*u+2]=v.z; w[4*u+3]=v.w;
                        }
                        #pragma unroll
                        for (int j = 0; j < 16; ++j) {
                            #pragma unroll
                            for (int i = 0; i < 16; ++i)
                                acc2[j] = __builtin_fmaf(a[i], w[i + j], acc2[j]);
                        }
                    }
                }
            }
            float t8[8], t4[4], t2[2], total;
            #pragma unroll
            for (int i = 0; i < 8; ++i) {
                float lo = acc2[2*i], hi = acc2[2*i+1];
                float keep = s0 ? hi : lo, send = s0 ? lo : hi;
                t8[i] = keep + __shfl_xor(send, 1);
            }
            #pragma unroll
            for (int i = 0; i < 4; ++i) {
                float lo = t8[2*i], hi = t8[2*i+1];
                float keep = s1 ? hi : lo, send = s1 ? lo : hi;
                t4[i] = keep + __shfl_xor(send, 2);
            }
            #pragma unroll
            for (int i = 0; i < 2; ++i) {
                float lo = t4[2*i], hi = t4[2*i+1];
                float keep = s2 ? hi : lo, send = s2 ? lo : hi;
                t2[i] = keep + __shfl_xor(send, 4);
            }
            {
                float lo = t2[0], hi = t2[1];
                float keep = s3 ? hi : lo, send = s3 ? lo : hi;
                total = keep + __shfl_xor(send, 8);
            }
            tot[r] = ((r << 6) + lane < N_LAGS) ? total : -__builtin_inff();
        }

        float w1 = tot[0], w2 = -__builtin_inff();
        int   j1 = lane;
        #pragma unroll
        for (int r = 1; r < 4; ++r) {
            float c = tot[r];
            bool take = (c > w1);
            float lose = take ? w1 : c;
            if (take) { w1 = c; j1 = (r << 6) + lane; }
            w2 = fmaxf(w2, lose);
        }
        #pragma unroll
        for (int m = 1; m < 64; m <<= 1) {
            float ov1 = __shfl_xor(w1, m);
            float ov2 = __shfl_xor(w2, m);
            int   oi1 = __shfl_xor(j1, m);
            bool take = (ov1 > w1) || (ov1 == w1 && oi1 < j1);
            float lose = take ? w1 : ov1;
            if (take) { w1 = ov1; j1 = oi1; }
            w2 = fmaxf(fmaxf(w2, ov2), lose);
        }

        if (w1 - w2 > GAP_B32) {
            if (lane == 0) {
                float period = (float)(j1 + MIN_PERIOD);
                float f0 = SR_F / (period + 1e-8f);
                out[bf] = fminf(fmaxf(f0, 50.0f), 500.0f);
            }
            continue;
        }

        // ============ tier-3: fp64 register tile (exact), rare ============
        double dtot[4];
        #pragma unroll
        for (int r = 0; r < 4; ++r) {
            const int g  = (r << 2) + qd;
            const int p0 = MIN_PERIOD + (g << 4);
            double dacc[16];
            #pragma unroll
            for (int j = 0; j < 16; ++j) dacc[j] = 0.0;
            if (g < 14) {
                const int n16 = (FRAME_LEN - p0 + 15) >> 4;
                #pragma unroll
                for (int k = 0; k < 2; ++k) {
                    const int ch = seg + (k << 4);
                    if (ch < n16) {
                        const int t  = ch << 4;
                        const int qa = t >> 2;
                        const int qw = (t + p0) >> 2;
                        float a[16], w[32];
                        #pragma unroll
                        for (int u = 0; u < 4; ++u) {
                            float4 v = s4[swz(qa + u)];
                            a[4*u+0]=v.x; a[4*u+1]=v.y; a[4*u+2]=v.z; a[4*u+3]=v.w;
                        }
                        #pragma unroll
                        for (int u = 0; u < 8; ++u) {
                            float4 v = s4[swz(qw + u)];
                            w[4*u+0]=v.x; w[4*u+1]=v.y; w[4*u+2]=v.z; w[4*u+3]=v.w;
                        }
                        #pragma unroll
                        for (int j = 0; j < 16; ++j) {
                            #pragma unroll
                            for (int i = 0; i < 16; ++i)
                                dacc[j] = fma((double)a[i], (double)w[i + j], dacc[j]);
                        }
                    }
                }
            }
            double u8[8], u4[4], u2[2], dtotal;
            #pragma unroll
            for (int i = 0; i < 8; ++i) {
                double lo = dacc[2*i], hi = dacc[2*i+1];
                double keep = s0 ? hi : lo, send = s0 ? lo : hi;
                u8[i] = keep + __shfl_xor(send, 1);
            }
            #pragma unroll
            for (int i = 0; i < 4; ++i) {
                double lo = u8[2*i], hi = u8[2*i+1];
                double keep = s1 ? hi : lo, send = s1 ? lo : hi;
                u4[i] = keep + __shfl_xor(send, 2);
            }
            #pragma unroll
            for (int i = 0; i < 2; ++i) {
                double lo = u4[2*i], hi = u4[2*i+1];
                double keep = s2 ? hi : lo, send = s2 ? lo : hi;
                u2[i] = keep + __shfl_xor(send, 4);
            }
            {
                double lo = u2[0], hi = u2[1];
                double keep = s3 ? hi : lo, send = s3 ? lo : hi;
                dtotal = keep + __shfl_xor(send, 8);
            }
            dtot[r] = ((r << 6) + lane < N_LAGS) ? dtotal : -__builtin_inf();
        }
        double dv1 = dtot[0];
        int    di1 = lane;
        #pragma unroll
        for (int r = 1; r < 4; ++r) {
            double c = dtot[r];
            if (c > dv1) { dv1 = c; di1 = (r << 6) + lane; }
        }
        #pragma unroll
        for (int m = 1; m < 64; m <<= 1) {
            double o = __shfl_xor(dv1, m);
            int   oi = __shfl_xor(di1, m);
            if (o > dv1 || (o == dv1 && oi < di1)) { dv1 = o; di1 = oi; }
        }
        if (lane == 0) {
            float period = (float)(di1 + MIN_PERIOD);
            float f0 = SR_F / (period + 1e-8f);
            out[bf] = fminf(fmaxf(f0, 50.0f), 500.0f);
        }
    }
}

extern "C" void kernel_launch(void* const* d_in, const int* in_sizes, int n_in,
                              void* d_out, int out_size, void* d_ws, size_t ws_size,
                              hipStream_t stream) {
    const float* wav = (const float*)d_in[0]; // (64, 1, 163840) fp32
    float* out = (float*)d_out;               // (64, 641) fp32
    const int n_blocks = (64 * N_FRAMES) / (WPB * FPW);   // 1282
    f0_kernel<<<n_blocks, 256, 0, stream>>>(wav, out);
}

// Round 12
// 223.837 us; speedup vs baseline: 1.2266x; 1.2266x over previous
//
#include <hip/hip_runtime.h>

// F0 via autocorrelation argmax — round 12: multi-frame waves + MFMA-only
// fallback (no fat VALU tile in the common path).
//   SR=16000, HOP=256, FRAME_LEN=512, pad=256, T=163840, B=64, n_frames=641
//   lags p in [32,256). Normalization is a positive per-frame scalar ->
//   argmax of RAW autocorrelation equals reference argmax.
//
// GEMM cast (validated r8-r11, absmax 0.0): y = frame zero-extended,
//   A[m,k]=y[k-16m], B[k,n]=y[k+32+n] => D[m,n]=AC[32+16m+n]
//   16 mfma_f32_16x16x32_f16 (K=512), two parity LDS copies for B-align.
//
// Round-11 lesson (counters): fp32 register-tile tier-2 (64 live floats,
// ~15% fire rate, inside the FPW loop) + compiler's 64-VGPR choice ->
// 224MB spill writes, 82->218us. Fix: tier-2 = r9's MFMA double-f16
// refinement (x=hi+lo; +16 hi*lo +16 lo*hi MFMAs; LDS only, no reg tile).
// lo copies staged lazily; per-wave slice 6400B, WPB=4 -> 25.6KB/block.
// Tier-3 fp64 register tile fires ~1-2%; its spill traffic is negligible
// (r9: WRITE_SIZE 2.5MB total).
//
// Tiers: accept iff top2 gap > 2*E; E1 = 2^-10*Q + 0.05 (f16 products via
// Cauchy-Schwarz, fp32 accum slack). E2 = 1e-4*Q + 0.02 (missing lo*lo
// <= 2^-22*Q; accum 1536*2^-24*Q). Tier-3 fp64: exact argmax (np-exact).

#define SR_F 16000.0f
#define HOP 256
#define FRAME_LEN 512
#define PAD 256
#define T_LEN 163840
#define N_FRAMES 641
#define MIN_PERIOD 32
#define N_LAGS 224
#define WPB 4            // waves per block
#define FPW 8            // frames per wave
#define GAP_B32 0.0625f

typedef _Float16 half8 __attribute__((ext_vector_type(8)));
typedef float floatx4 __attribute__((ext_vector_type(4)));

__device__ __forceinline__ int swz(int q) { return q ^ ((q >> 3) & 7); }

__device__ __forceinline__ unsigned int pkh(float a, float b) {
    unsigned short ha = __builtin_bit_cast(unsigned short, (_Float16)a);
    unsigned short hb = __builtin_bit_cast(unsigned short, (_Float16)b);
    return (unsigned int)ha | ((unsigned int)hb << 16);
}

// stage parity copies: even (elem e = Y[e-240]) + odd (elem e = Y[e-239])
__device__ __forceinline__ void write_copies(unsigned int* e, unsigned int* o,
                                             unsigned int u10, unsigned int u11,
                                             unsigned int u20, unsigned int u21,
                                             int lane) {
    e[120 + 2*lane] = u10;  e[121 + 2*lane] = u11;
    e[248 + 2*lane] = u20;  e[249 + 2*lane] = u21;
    unsigned int a  = __shfl(u10, (lane + 1) & 63);
    unsigned int bb = __shfl(u20, (lane + 1) & 63);
    unsigned int n1 = (lane == 63) ? bb : a;
    unsigned int n2 = (lane == 63) ? 0u : bb;
    o[120 + 2*lane] = (u10 >> 16) | (u11 << 16);
    o[121 + 2*lane] = (u11 >> 16) | (n1 << 16);
    o[248 + 2*lane] = (u20 >> 16) | (u21 << 16);
    o[249 + 2*lane] = (u21 >> 16) | (n2 << 16);
    if (lane == 0) o[119] = u10 << 16;   // {Y[-1]=0, Y[0]}
}

__global__ __launch_bounds__(256, 4) void f0_kernel(const float* __restrict__ wav,
                                                    float* __restrict__ out) {
    // per-wave slice: ye(400) yo(400) le(400) lo(400) dwords = 6400 B
    __shared__ unsigned int yw[WPB][1600];

    const int tid  = threadIdx.x;
    const int wv   = tid >> 6;
    const int lane = tid & 63;
    unsigned int* ye  = yw[wv];
    unsigned int* yo  = ye + 400;
    unsigned int* le  = ye + 800;
    unsigned int* loo = ye + 1200;

    const int qd = lane >> 4;       // quad
    const int nn = lane & 15;       // A-row m / B-col n
    const int par = nn & 1;
    const unsigned int* ybh = par ? yo : ye;
    const unsigned int* ybl = par ? loo : le;
    const int wA0 = 120 + 4*qd - 8*nn;
    const int wB0 = 136 + 4*qd + ((nn - par) >> 1);
    const int seg = lane & 15;
    const bool s0 = (seg & 1), s1 = (seg & 2), s2 = (seg & 4), s3 = (seg & 8);

    const int bf0 = (blockIdx.x * WPB + wv) * FPW;   // 1282*4*8 == 41024

    for (int it = 0; it < FPW; ++it) {
        const int bf = bf0 + it;
        const int b  = bf / N_FRAMES;
        const int f  = bf - b * N_FRAMES;
        const float* __restrict__ x = wav + (size_t)b * T_LEN;
        const int base = f * HOP - PAD;
        const bool fast = (f != 0 && f != N_FRAMES - 1);

        // ---- stage frame (f16 hi, two parity copies) ----
        float4 c1, c2;
        if (fast) {
            const float4* g4 = (const float4*)(x + base);
            c1 = g4[lane];
            c2 = g4[lane + 64];
        }
        ye[lane] = 0u; yo[lane] = 0u;
        if (lane < 56) { ye[64 + lane] = 0u; yo[64 + lane] = 0u; }
        if (lane < 25) { ye[375 + lane] = 0u; yo[375 + lane] = 0u; }

        float qen = 0.0f;
        if (fast) {
            qen = c1.x*c1.x + c1.y*c1.y + c1.z*c1.z + c1.w*c1.w
                + c2.x*c2.x + c2.y*c2.y + c2.z*c2.z + c2.w*c2.w;
            write_copies(ye, yo, pkh(c1.x, c1.y), pkh(c1.z, c1.w),
                                 pkh(c2.x, c2.y), pkh(c2.z, c2.w), lane);
        } else {
            for (int t = lane; t < FRAME_LEN; t += 64) {
                int idx = base + t;
                if (idx < 0) idx = -idx;
                if (idx >= T_LEN) idx = 2 * (T_LEN - 1) - idx;
                float v = x[idx];
                qen = __builtin_fmaf(v, v, qen);
                unsigned short h = __builtin_bit_cast(unsigned short, (_Float16)v);
                ((unsigned short*)ye)[240 + t] = h;
                ((unsigned short*)yo)[239 + t] = h;
            }
        }
        __threadfence_block();

        #pragma unroll
        for (int m = 1; m < 64; m <<= 1) qen += __shfl_xor(qen, m);

        // ---------------- tier-1: 16 MFMA (2 chains) ----------------
        floatx4 acc0 = {0.f, 0.f, 0.f, 0.f};
        floatx4 acc1 = {0.f, 0.f, 0.f, 0.f};
        #pragma unroll
        for (int c = 0; c < 16; c += 2) {
            uint4 au0 = *(const uint4*)(ye + (wA0 + 16*c));
            const unsigned int* pb0 = ybh + (wB0 + 16*c);
            uint4 bu0; bu0.x=pb0[0]; bu0.y=pb0[1]; bu0.z=pb0[2]; bu0.w=pb0[3];
            uint4 au1 = *(const uint4*)(ye + (wA0 + 16*(c+1)));
            const unsigned int* pb1 = ybh + (wB0 + 16*(c+1));
            uint4 bu1; bu1.x=pb1[0]; bu1.y=pb1[1]; bu1.z=pb1[2]; bu1.w=pb1[3];
            acc0 = __builtin_amdgcn_mfma_f32_16x16x32_f16(
                __builtin_bit_cast(half8, au0), __builtin_bit_cast(half8, bu0),
                acc0, 0, 0, 0);
            acc1 = __builtin_amdgcn_mfma_f32_16x16x32_f16(
                __builtin_bit_cast(half8, au1), __builtin_bit_cast(half8, bu1),
                acc1, 0, 0, 0);
        }
        floatx4 acc = acc0 + acc1;

        // ---- top-2 (per-lane over 4 regs, then 64-lane butterfly) ----
        float v1 = acc[0];
        int   i1 = 64*qd + nn;
        float v2 = -__builtin_inff();
        #pragma unroll
        for (int r = 1; r < 4; ++r) {
            float cv = (4*qd + r < 14) ? acc[r] : -__builtin_inff();
            bool take = (cv > v1);
            float lose = take ? v1 : cv;
            if (take) { v1 = cv; i1 = 64*qd + 16*r + nn; }
            v2 = fmaxf(v2, lose);
        }
        #pragma unroll
        for (int m = 1; m < 64; m <<= 1) {
            float ov1 = __shfl_xor(v1, m);
            float ov2 = __shfl_xor(v2, m);
            int   oi1 = __shfl_xor(i1, m);
            bool take = (ov1 > v1) || (ov1 == v1 && oi1 < i1);
            float lose = take ? v1 : ov1;
            if (take) { v1 = ov1; i1 = oi1; }
            v2 = fmaxf(fmaxf(v2, ov2), lose);
        }

        const float E1 = 9.765625e-4f * qen + 0.05f;
        if (v1 - v2 > 2.0f * E1) {
            if (lane == 0) {
                float period = (float)(i1 + MIN_PERIOD);
                float f0 = SR_F / (period + 1e-8f);
                out[bf] = fminf(fmaxf(f0, 50.0f), 500.0f);
            }
            continue;
        }

        // ==== tier-2: double-f16 split, +32 MFMA (hi*lo + lo*hi), ~15% ====
        le[lane] = 0u; loo[lane] = 0u;
        if (lane < 56) { le[64 + lane] = 0u; loo[64 + lane] = 0u; }
        if (lane < 25) { le[375 + lane] = 0u; loo[375 + lane] = 0u; }
        if (fast) {
            float l0 = c1.x - (float)(_Float16)c1.x;
            float l1 = c1.y - (float)(_Float16)c1.y;
            float l2 = c1.z - (float)(_Float16)c1.z;
            float l3 = c1.w - (float)(_Float16)c1.w;
            float l4 = c2.x - (float)(_Float16)c2.x;
            float l5 = c2.y - (float)(_Float16)c2.y;
            float l6 = c2.z - (float)(_Float16)c2.z;
            float l7 = c2.w - (float)(_Float16)c2.w;
            write_copies(le, loo, pkh(l0, l1), pkh(l2, l3),
                                  pkh(l4, l5), pkh(l6, l7), lane);
        } else {
            for (int t = lane; t < FRAME_LEN; t += 64) {
                int idx = base + t;
                if (idx < 0) idx = -idx;
                if (idx >= T_LEN) idx = 2 * (T_LEN - 1) - idx;
                float v = x[idx];
                float l = v - (float)(_Float16)v;
                unsigned short h = __builtin_bit_cast(unsigned short, (_Float16)l);
                ((unsigned short*)le)[240 + t] = h;
                ((unsigned short*)loo)[239 + t] = h;
            }
        }
        __threadfence_block();

        #pragma unroll
        for (int c = 0; c < 16; ++c) {              // hi * lo
            uint4 au = *(const uint4*)(ye + (wA0 + 16*c));
            const unsigned int* pb = ybl + (wB0 + 16*c);
            uint4 bu; bu.x = pb[0]; bu.y = pb[1]; bu.z = pb[2]; bu.w = pb[3];
            acc = __builtin_amdgcn_mfma_f32_16x16x32_f16(
                __builtin_bit_cast(half8, au), __builtin_bit_cast(half8, bu),
                acc, 0, 0, 0);
        }
        #pragma unroll
        for (int c = 0; c < 16; ++c) {              // lo * hi
            uint4 au = *(const uint4*)(le + (wA0 + 16*c));
            const unsigned int* pb = ybh + (wB0 + 16*c);
            uint4 bu; bu.x = pb[0]; bu.y = pb[1]; bu.z = pb[2]; bu.w = pb[3];
            acc = __builtin_amdgcn_mfma_f32_16x16x32_f16(
                __builtin_bit_cast(half8, au), __builtin_bit_cast(half8, bu),
                acc, 0, 0, 0);
        }

        v1 = acc[0]; i1 = 64*qd + nn; v2 = -__builtin_inff();
        #pragma unroll
        for (int r = 1; r < 4; ++r) {
            float cv = (4*qd + r < 14) ? acc[r] : -__builtin_inff();
            bool take = (cv > v1);
            float lose = take ? v1 : cv;
            if (take) { v1 = cv; i1 = 64*qd + 16*r + nn; }
            v2 = fmaxf(v2, lose);
        }
        #pragma unroll
        for (int m = 1; m < 64; m <<= 1) {
            float ov1 = __shfl_xor(v1, m);
            float ov2 = __shfl_xor(v2, m);
            int   oi1 = __shfl_xor(i1, m);
            bool take = (ov1 > v1) || (ov1 == v1 && oi1 < i1);
            float lose = take ? v1 : ov1;
            if (take) { v1 = ov1; i1 = oi1; }
            v2 = fmaxf(fmaxf(v2, ov2), lose);
        }

        const float E2 = 1.0e-4f * qen + 0.02f;
        if (v1 - v2 > 2.0f * E2) {
            if (lane == 0) {
                float period = (float)(i1 + MIN_PERIOD);
                float f0 = SR_F / (period + 1e-8f);
                out[bf] = fminf(fmaxf(f0, 50.0f), 500.0f);
            }
            continue;
        }

        // ============ tier-3: fp64 register tile (exact), ~1-2% ============
        float* sw = (float*)ye;   // 576 floats over ye+yo; restaged next iter
        if (fast) {
            const float4* g4 = (const float4*)(x + base);   // L2-hot reload
            ((float4*)sw)[swz(lane)]      = g4[lane];
            ((float4*)sw)[swz(lane + 64)] = g4[lane + 64];
            if (lane < 16) ((float4*)sw)[swz(lane + 128)] = make_float4(0.f,0.f,0.f,0.f);
        } else {
            for (int t = lane; t < FRAME_LEN; t += 64) {
                int idx = base + t;
                if (idx < 0) idx = -idx;
                if (idx >= T_LEN) idx = 2 * (T_LEN - 1) - idx;
                sw[(swz(t >> 2) << 2) | (t & 3)] = x[idx];
            }
            int t = FRAME_LEN + lane;
            sw[(swz(t >> 2) << 2) | (t & 3)] = 0.0f;
        }
        __threadfence_block();

        const float4* s4 = (const float4*)sw;
        double dtot[4];
        #pragma unroll
        for (int r = 0; r < 4; ++r) {
            const int g  = (r << 2) + qd;
            const int p0 = MIN_PERIOD + (g << 4);
            double dacc[16];
            #pragma unroll
            for (int j = 0; j < 16; ++j) dacc[j] = 0.0;
            if (g < 14) {
                const int n16 = (FRAME_LEN - p0 + 15) >> 4;
                #pragma unroll
                for (int k = 0; k < 2; ++k) {
                    const int ch = seg + (k << 4);
                    if (ch < n16) {
                        const int t  = ch << 4;
                        const int qa = t >> 2;
                        const int qw = (t + p0) >> 2;
                        float a[16], w[32];
                        #pragma unroll
                        for (int u = 0; u < 4; ++u) {
                            float4 v = s4[swz(qa + u)];
                            a[4*u+0]=v.x; a[4*u+1]=v.y; a[4*u+2]=v.z; a[4*u+3]=v.w;
                        }
                        #pragma unroll
                        for (int u = 0; u < 8; ++u) {
                            float4 v = s4[swz(qw + u)];
                            w[4*u+0]=v.x; w[4*u+1]=v.y; w[4*u+2]=v.z; w[4*u+3]=v.w;
                        }
                        #pragma unroll
                        for (int j = 0; j < 16; ++j) {
                            #pragma unroll
                            for (int i = 0; i < 16; ++i)
                                dacc[j] = fma((double)a[i], (double)w[i + j], dacc[j]);
                        }
                    }
                }
            }
            double u8[8], u4[4], u2[2], dtotal;
            #pragma unroll
            for (int i = 0; i < 8; ++i) {
                double lo = dacc[2*i], hi = dacc[2*i+1];
                double keep = s0 ? hi : lo, send = s0 ? lo : hi;
                u8[i] = keep + __shfl_xor(send, 1);
            }
            #pragma unroll
            for (int i = 0; i < 4; ++i) {
                double lo = u8[2*i], hi = u8[2*i+1];
                double keep = s1 ? hi : lo, send = s1 ? lo : hi;
                u4[i] = keep + __shfl_xor(send, 2);
            }
            #pragma unroll
            for (int i = 0; i < 2; ++i) {
                double lo = u4[2*i], hi = u4[2*i+1];
                double keep = s2 ? hi : lo, send = s2 ? lo : hi;
                u2[i] = keep + __shfl_xor(send, 4);
            }
            {
                double lo = u2[0], hi = u2[1];
                double keep = s3 ? hi : lo, send = s3 ? lo : hi;
                dtotal = keep + __shfl_xor(send, 8);
            }
            dtot[r] = ((r << 6) + lane < N_LAGS) ? dtotal : -__builtin_inf();
        }
        double dv1 = dtot[0];
        int    di1 = lane;
        #pragma unroll
        for (int r = 1; r < 4; ++r) {
            double c = dtot[r];
            if (c > dv1) { dv1 = c; di1 = (r << 6) + lane; }
        }
        #pragma unroll
        for (int m = 1; m < 64; m <<= 1) {
            double o = __shfl_xor(dv1, m);
            int   oi = __shfl_xor(di1, m);
            if (o > dv1 || (o == dv1 && oi < di1)) { dv1 = o; di1 = oi; }
        }
        if (lane == 0) {
            float period = (float)(di1 + MIN_PERIOD);
            float f0 = SR_F / (period + 1e-8f);
            out[bf] = fminf(fmaxf(f0, 50.0f), 500.0f);
        }
    }
}

extern "C" void kernel_launch(void* const* d_in, const int* in_sizes, int n_in,
                              void* d_out, int out_size, void* d_ws, size_t ws_size,
                              hipStream_t stream) {
    const float* wav = (const float*)d_in[0]; // (64, 1, 163840) fp32
    float* out = (float*)d_out;               // (64, 641) fp32
    const int n_blocks = (64 * N_FRAMES) / (WPB * FPW);   // 1282
    f0_kernel<<<n_blocks, 256, 0, stream>>>(wav, out);
}

// Round 13
// 133.111 us; speedup vs baseline: 2.0626x; 1.6816x over previous
//
#include <hip/hip_runtime.h>

// F0 via autocorrelation argmax — round 13: straight-line 3-tier MFMA,
// 4-wave blocks, XCD-contiguous frame assignment.
//   SR=16000, HOP=256, FRAME_LEN=512, pad=256, T=163840, B=64, n_frames=641
//   lags p in [32,256). Normalization is a positive per-frame scalar ->
//   argmax of RAW autocorrelation equals reference argmax.
//
// GEMM cast (validated r8-r12, absmax 0.0): y = frame zero-extended,
//   A[m,k]=y[k-16m], B[k,n]=y[k+32+n] => D[m,n]=AC[32+16m+n]
//   16 mfma_f32_16x16x32_f16 (K=512), two parity LDS copies for B-align.
//
// Round-11/12 lesson (counters): ANY per-wave multi-frame loop makes the
// allocator emit hot-path spill code (~6KB/iter -> 224-249MB writes).
// Straight-line kernels (r8/r9) never spilled. So: straight-line body,
// one frame per wave. Residency fixes vs r9:
//   - 256-thread blocks (4 waves, 25.6KB LDS) -> finer LDS release, less
//     straggler holding than r9's 8-wave/51.2KB blocks.
//   - XCD swizzle: 10256 blocks = 8*1282; xcd=blockIdx&7 gets a contiguous
//     run of 1282 block-slots = 8 batch-rows (~5MB) -> staging hits L2
//     (~200cyc) instead of HBM (~900cyc), shortening the unhidden
//     per-wave critical path.
//
// Tiers: accept iff top2 gap > 2*E; E1 = 2^-10*Q + 0.05 (f16 products via
// Cauchy-Schwarz, fp32 accum slack; covers 2-chain reassociation).
// Tier-2: double-f16 split, +32 MFMA (hi*lo + lo*hi), E2 = 1e-4*Q + 0.02.
// Tier-3: fp64 register tile, exact argmax (np-exact r1-r12); its spill
// code is cold (fires ~1-2%).

#define SR_F 16000.0f
#define HOP 256
#define FRAME_LEN 512
#define PAD 256
#define T_LEN 163840
#define N_FRAMES 641
#define MIN_PERIOD 32
#define N_LAGS 224
#define WPB 4            // waves per block, one frame per wave

typedef _Float16 half8 __attribute__((ext_vector_type(8)));
typedef float floatx4 __attribute__((ext_vector_type(4)));

__device__ __forceinline__ int swz(int q) { return q ^ ((q >> 3) & 7); }

__device__ __forceinline__ unsigned int pkh(float a, float b) {
    unsigned short ha = __builtin_bit_cast(unsigned short, (_Float16)a);
    unsigned short hb = __builtin_bit_cast(unsigned short, (_Float16)b);
    return (unsigned int)ha | ((unsigned int)hb << 16);
}

// stage parity copies: even (elem e = Y[e-240]) + odd (elem e = Y[e-239])
__device__ __forceinline__ void write_copies(unsigned int* e, unsigned int* o,
                                             unsigned int u10, unsigned int u11,
                                             unsigned int u20, unsigned int u21,
                                             int lane) {
    e[120 + 2*lane] = u10;  e[121 + 2*lane] = u11;
    e[248 + 2*lane] = u20;  e[249 + 2*lane] = u21;
    unsigned int a  = __shfl(u10, (lane + 1) & 63);
    unsigned int bb = __shfl(u20, (lane + 1) & 63);
    unsigned int n1 = (lane == 63) ? bb : a;
    unsigned int n2 = (lane == 63) ? 0u : bb;
    o[120 + 2*lane] = (u10 >> 16) | (u11 << 16);
    o[121 + 2*lane] = (u11 >> 16) | (n1 << 16);
    o[248 + 2*lane] = (u20 >> 16) | (u21 << 16);
    o[249 + 2*lane] = (u21 >> 16) | (n2 << 16);
    if (lane == 0) o[119] = u10 << 16;   // {Y[-1]=0, Y[0]}
}

__global__ __launch_bounds__(256, 4) void f0_kernel(const float* __restrict__ wav,
                                                    float* __restrict__ out) {
    // per-wave slice: ye(400) yo(400) le(400) lo(400) dwords = 6400 B
    __shared__ unsigned int yw[WPB][1600];

    const int tid  = threadIdx.x;
    const int wv   = tid >> 6;
    const int lane = tid & 63;
    unsigned int* ye  = yw[wv];
    unsigned int* yo  = ye + 400;
    unsigned int* le  = ye + 800;
    unsigned int* loo = ye + 1200;

    // XCD-contiguous frame assignment: 10256 blocks = 8 XCDs * 1282 slots.
    // Blocks on XCD g (round-robin blockIdx%8) cover a contiguous bf range
    // [g*5128, (g+1)*5128) = 8 whole batch-rows -> L2-resident staging.
    const int xcd = blockIdx.x & 7;
    const int idx = blockIdx.x >> 3;
    const int bf  = (xcd * 1282 + idx) * WPB + wv;   // all 41024 covered
    const int b   = bf / N_FRAMES;
    const int f   = bf - b * N_FRAMES;
    const float* __restrict__ x = wav + (size_t)b * T_LEN;
    const int base = f * HOP - PAD;
    const bool fast = (f != 0 && f != N_FRAMES - 1);

    const int qd = lane >> 4;       // quad
    const int nn = lane & 15;       // A-row m / B-col n
    const int par = nn & 1;
    const unsigned int* ybh = par ? yo : ye;
    const unsigned int* ybl = par ? loo : le;
    const int wA0 = 120 + 4*qd - 8*nn;
    const int wB0 = 136 + 4*qd + ((nn - par) >> 1);
    const int seg = lane & 15;
    const bool s0 = (seg & 1), s1 = (seg & 2), s2 = (seg & 4), s3 = (seg & 8);

    // ---- issue global loads first ----
    float4 c1, c2;
    if (fast) {
        const float4* g4 = (const float4*)(x + base);   // aligned, in-bounds
        c1 = g4[lane];
        c2 = g4[lane + 64];
    }
    // zero margins: dwords [0,120) and [375,400) of both parity copies
    ye[lane] = 0u; yo[lane] = 0u;
    if (lane < 56) { ye[64 + lane] = 0u; yo[64 + lane] = 0u; }
    if (lane < 25) { ye[375 + lane] = 0u; yo[375 + lane] = 0u; }

    float qen = 0.0f;
    if (fast) {
        qen = c1.x*c1.x + c1.y*c1.y + c1.z*c1.z + c1.w*c1.w
            + c2.x*c2.x + c2.y*c2.y + c2.z*c2.z + c2.w*c2.w;
        write_copies(ye, yo, pkh(c1.x, c1.y), pkh(c1.z, c1.w),
                             pkh(c2.x, c2.y), pkh(c2.z, c2.w), lane);
    } else {
        for (int t = lane; t < FRAME_LEN; t += 64) {
            int idxr = base + t;
            if (idxr < 0) idxr = -idxr;
            if (idxr >= T_LEN) idxr = 2 * (T_LEN - 1) - idxr;
            float v = x[idxr];
            qen = __builtin_fmaf(v, v, qen);
            unsigned short h = __builtin_bit_cast(unsigned short, (_Float16)v);
            ((unsigned short*)ye)[240 + t] = h;
            ((unsigned short*)yo)[239 + t] = h;
        }
    }
    __threadfence_block();

    #pragma unroll
    for (int m = 1; m < 64; m <<= 1) qen += __shfl_xor(qen, m);

    // ---------------- tier-1: 16 MFMA (2 chains) ----------------
    floatx4 acc0 = {0.f, 0.f, 0.f, 0.f};
    floatx4 acc1 = {0.f, 0.f, 0.f, 0.f};
    #pragma unroll
    for (int c = 0; c < 16; c += 2) {
        uint4 au0 = *(const uint4*)(ye + (wA0 + 16*c));
        const unsigned int* pb0 = ybh + (wB0 + 16*c);
        uint4 bu0; bu0.x=pb0[0]; bu0.y=pb0[1]; bu0.z=pb0[2]; bu0.w=pb0[3];
        uint4 au1 = *(const uint4*)(ye + (wA0 + 16*(c+1)));
        const unsigned int* pb1 = ybh + (wB0 + 16*(c+1));
        uint4 bu1; bu1.x=pb1[0]; bu1.y=pb1[1]; bu1.z=pb1[2]; bu1.w=pb1[3];
        acc0 = __builtin_amdgcn_mfma_f32_16x16x32_f16(
            __builtin_bit_cast(half8, au0), __builtin_bit_cast(half8, bu0),
            acc0, 0, 0, 0);
        acc1 = __builtin_amdgcn_mfma_f32_16x16x32_f16(
            __builtin_bit_cast(half8, au1), __builtin_bit_cast(half8, bu1),
            acc1, 0, 0, 0);
    }
    floatx4 acc = acc0 + acc1;

    // ---- top-2 (per-lane over 4 regs, then 64-lane butterfly) ----
    float v1 = acc[0];
    int   i1 = 64*qd + nn;
    float v2 = -__builtin_inff();
    #pragma unroll
    for (int r = 1; r < 4; ++r) {
        float cv = (4*qd + r < 14) ? acc[r] : -__builtin_inff();
        bool take = (cv > v1);
        float lose = take ? v1 : cv;
        if (take) { v1 = cv; i1 = 64*qd + 16*r + nn; }
        v2 = fmaxf(v2, lose);
    }
    #pragma unroll
    for (int m = 1; m < 64; m <<= 1) {
        float ov1 = __shfl_xor(v1, m);
        float ov2 = __shfl_xor(v2, m);
        int   oi1 = __shfl_xor(i1, m);
        bool take = (ov1 > v1) || (ov1 == v1 && oi1 < i1);
        float lose = take ? v1 : ov1;
        if (take) { v1 = ov1; i1 = oi1; }
        v2 = fmaxf(fmaxf(v2, ov2), lose);
    }

    const float E1 = 9.765625e-4f * qen + 0.05f;
    if (v1 - v2 > 2.0f * E1) {
        if (lane == 0) {
            float period = (float)(i1 + MIN_PERIOD);
            float f0 = SR_F / (period + 1e-8f);
            out[bf] = fminf(fmaxf(f0, 50.0f), 500.0f);
        }
        return;
    }

    // ==== tier-2: double-f16 split, +32 MFMA (hi*lo + lo*hi), ~15% ====
    le[lane] = 0u; loo[lane] = 0u;
    if (lane < 56) { le[64 + lane] = 0u; loo[64 + lane] = 0u; }
    if (lane < 25) { le[375 + lane] = 0u; loo[375 + lane] = 0u; }
    if (fast) {
        float l0 = c1.x - (float)(_Float16)c1.x;
        float l1 = c1.y - (float)(_Float16)c1.y;
        float l2 = c1.z - (float)(_Float16)c1.z;
        float l3 = c1.w - (float)(_Float16)c1.w;
        float l4 = c2.x - (float)(_Float16)c2.x;
        float l5 = c2.y - (float)(_Float16)c2.y;
        float l6 = c2.z - (float)(_Float16)c2.z;
        float l7 = c2.w - (float)(_Float16)c2.w;
        write_copies(le, loo, pkh(l0, l1), pkh(l2, l3),
                              pkh(l4, l5), pkh(l6, l7), lane);
    } else {
        for (int t = lane; t < FRAME_LEN; t += 64) {
            int idxr = base + t;
            if (idxr < 0) idxr = -idxr;
            if (idxr >= T_LEN) idxr = 2 * (T_LEN - 1) - idxr;
            float v = x[idxr];
            float l = v - (float)(_Float16)v;
            unsigned short h = __builtin_bit_cast(unsigned short, (_Float16)l);
            ((unsigned short*)le)[240 + t] = h;
            ((unsigned short*)loo)[239 + t] = h;
        }
    }
    __threadfence_block();

    #pragma unroll
    for (int c = 0; c < 16; ++c) {              // hi * lo
        uint4 au = *(const uint4*)(ye + (wA0 + 16*c));
        const unsigned int* pb = ybl + (wB0 + 16*c);
        uint4 bu; bu.x = pb[0]; bu.y = pb[1]; bu.z = pb[2]; bu.w = pb[3];
        acc = __builtin_amdgcn_mfma_f32_16x16x32_f16(
            __builtin_bit_cast(half8, au), __builtin_bit_cast(half8, bu),
            acc, 0, 0, 0);
    }
    #pragma unroll
    for (int c = 0; c < 16; ++c) {              // lo * hi
        uint4 au = *(const uint4*)(le + (wA0 + 16*c));
        const unsigned int* pb = ybh + (wB0 + 16*c);
        uint4 bu; bu.x = pb[0]; bu.y = pb[1]; bu.z = pb[2]; bu.w = pb[3];
        acc = __builtin_amdgcn_mfma_f32_16x16x32_f16(
            __builtin_bit_cast(half8, au), __builtin_bit_cast(half8, bu),
            acc, 0, 0, 0);
    }

    v1 = acc[0]; i1 = 64*qd + nn; v2 = -__builtin_inff();
    #pragma unroll
    for (int r = 1; r < 4; ++r) {
        float cv = (4*qd + r < 14) ? acc[r] : -__builtin_inff();
        bool take = (cv > v1);
        float lose = take ? v1 : cv;
        if (take) { v1 = cv; i1 = 64*qd + 16*r + nn; }
        v2 = fmaxf(v2, lose);
    }
    #pragma unroll
    for (int m = 1; m < 64; m <<= 1) {
        float ov1 = __shfl_xor(v1, m);
        float ov2 = __shfl_xor(v2, m);
        int   oi1 = __shfl_xor(i1, m);
        bool take = (ov1 > v1) || (ov1 == v1 && oi1 < i1);
        float lose = take ? v1 : ov1;
        if (take) { v1 = ov1; i1 = oi1; }
        v2 = fmaxf(fmaxf(v2, ov2), lose);
    }

    const float E2 = 1.0e-4f * qen + 0.02f;
    if (v1 - v2 > 2.0f * E2) {
        if (lane == 0) {
            float period = (float)(i1 + MIN_PERIOD);
            float f0 = SR_F / (period + 1e-8f);
            out[bf] = fminf(fmaxf(f0, 50.0f), 500.0f);
        }
        return;
    }

    // ============ tier-3: fp64 register tile (exact), ~1-2% ============
    float* sw = (float*)ye;   // 576 floats over ye+yo (terminal use)
    if (fast) {
        const float4* g4 = (const float4*)(x + base);   // L2-hot reload
        ((float4*)sw)[swz(lane)]      = g4[lane];
        ((float4*)sw)[swz(lane + 64)] = g4[lane + 64];
        if (lane < 16) ((float4*)sw)[swz(lane + 128)] = make_float4(0.f,0.f,0.f,0.f);
    } else {
        for (int t = lane; t < FRAME_LEN; t += 64) {
            int idxr = base + t;
            if (idxr < 0) idxr = -idxr;
            if (idxr >= T_LEN) idxr = 2 * (T_LEN - 1) - idxr;
            sw[(swz(t >> 2) << 2) | (t & 3)] = x[idxr];
        }
        int t = FRAME_LEN + lane;
        sw[(swz(t >> 2) << 2) | (t & 3)] = 0.0f;
    }
    __threadfence_block();

    const float4* s4 = (const float4*)sw;
    double dtot[4];
    #pragma unroll
    for (int r = 0; r < 4; ++r) {
        const int g  = (r << 2) + qd;
        const int p0 = MIN_PERIOD + (g << 4);
        double dacc[16];
        #pragma unroll
        for (int j = 0; j < 16; ++j) dacc[j] = 0.0;
        if (g < 14) {
            const int n16 = (FRAME_LEN - p0 + 15) >> 4;
            #pragma unroll
            for (int k = 0; k < 2; ++k) {
                const int ch = seg + (k << 4);
                if (ch < n16) {
                    const int t  = ch << 4;
                    const int qa = t >> 2;
                    const int qw = (t + p0) >> 2;
                    float a[16], w[32];
                    #pragma unroll
                    for (int u = 0; u < 4; ++u) {
                        float4 v = s4[swz(qa + u)];
                        a[4*u+0]=v.x; a[4*u+1]=v.y; a[4*u+2]=v.z; a[4*u+3]=v.w;
                    }
                    #pragma unroll
                    for (int u = 0; u < 8; ++u) {
                        float4 v = s4[swz(qw + u)];
                        w[4*u+0]=v.x; w[4*u+1]=v.y; w[4*u+2]=v.z; w[4*u+3]=v.w;
                    }
                    #pragma unroll
                    for (int j = 0; j < 16; ++j) {
                        #pragma unroll
                        for (int i = 0; i < 16; ++i)
                            dacc[j] = fma((double)a[i], (double)w[i + j], dacc[j]);
                    }
                }
            }
        }
        double u8[8], u4[4], u2[2], dtotal;
        #pragma unroll
        for (int i = 0; i < 8; ++i) {
            double lo = dacc[2*i], hi = dacc[2*i+1];
            double keep = s0 ? hi : lo, send = s0 ? lo : hi;
            u8[i] = keep + __shfl_xor(send, 1);
        }
        #pragma unroll
        for (int i = 0; i < 4; ++i) {
            double lo = u8[2*i], hi = u8[2*i+1];
            double keep = s1 ? hi : lo, send = s1 ? lo : hi;
            u4[i] = keep + __shfl_xor(send, 2);
        }
        #pragma unroll
        for (int i = 0; i < 2; ++i) {
            double lo = u4[2*i], hi = u4[2*i+1];
            double keep = s2 ? hi : lo, send = s2 ? lo : hi;
            u2[i] = keep + __shfl_xor(send, 4);
        }
        {
            double lo = u2[0], hi = u2[1];
            double keep = s3 ? hi : lo, send = s3 ? lo : hi;
            dtotal = keep + __shfl_xor(send, 8);
        }
        dtot[r] = ((r << 6) + lane < N_LAGS) ? dtotal : -__builtin_inf();
    }
    double dv1 = dtot[0];
    int    di1 = lane;
    #pragma unroll
    for (int r = 1; r < 4; ++r) {
        double c = dtot[r];
        if (c > dv1) { dv1 = c; di1 = (r << 6) + lane; }
    }
    #pragma unroll
    for (int m = 1; m < 64; m <<= 1) {
        double o = __shfl_xor(dv1, m);
        int   oi = __shfl_xor(di1, m);
        if (o > dv1 || (o == dv1 && oi < di1)) { dv1 = o; di1 = oi; }
    }
    if (lane == 0) {
        float period = (float)(di1 + MIN_PERIOD);
        float f0 = SR_F / (period + 1e-8f);
        out[bf] = fminf(fmaxf(f0, 50.0f), 500.0f);
    }
}

extern "C" void kernel_launch(void* const* d_in, const int* in_sizes, int n_in,
                              void* d_out, int out_size, void* d_ws, size_t ws_size,
                              hipStream_t stream) {
    const float* wav = (const float*)d_in[0]; // (64, 1, 163840) fp32
    float* out = (float*)d_out;               // (64, 641) fp32
    const int n_blocks = (64 * N_FRAMES) / WPB;   // 10256 = 8 * 1282
    f0_kernel<<<n_blocks, 256, 0, stream>>>(wav, out);
}